// Round 5
// baseline (621.846 us; speedup 1.0000x reference)
//
#include <hip/hip_runtime.h>

#define M_DIM 8192
#define N_DIM 4096
#define K_DIM 4096

typedef _Float16 f16;
typedef _Float16 f16x8 __attribute__((ext_vector_type(8)));
typedef float f32x16 __attribute__((ext_vector_type(16)));

// async global->LDS, 16B per lane. LDS dest is wave-uniform base; HW stores lane i at base + i*16.
__device__ __forceinline__ void lds_async16(void* lds, const void* g) {
    __builtin_amdgcn_global_load_lds(
        (const __attribute__((address_space(1))) void*)(void*)g,
        (__attribute__((address_space(3))) void*)lds, 16, 0, 0);
}

// ---- prepass: packed int4 (one byte per int32, hi nibble first) -> f16 Q in [-8,7] ----
__global__ __launch_bounds__(256) void cvt_w_kernel(const int* __restrict__ pw, f16* __restrict__ wh) {
    size_t idx = (size_t)blockIdx.x * 256 + threadIdx.x;  // 4 ints / thread -> 8 halves
    int4 v = ((const int4*)pw)[idx];
    f16x8 h;
    int a;
    a = v.x; h[0] = (f16)(((a >> 4) & 15) - 8); h[1] = (f16)((a & 15) - 8);
    a = v.y; h[2] = (f16)(((a >> 4) & 15) - 8); h[3] = (f16)((a & 15) - 8);
    a = v.z; h[4] = (f16)(((a >> 4) & 15) - 8); h[5] = (f16)((a & 15) - 8);
    a = v.w; h[6] = (f16)(((a >> 4) & 15) - 8); h[7] = (f16)((a & 15) - 8);
    *(f16x8*)(wh + idx * 8) = h;
}

// ---- main GEMM: C[M,N] = sw * (x[M,K] @ W[N,K]^T) + bias[N], fp32->f16 A-convert FUSED ----
// R0-proven 128x128 tile, 4 waves (2x2 of 64x64), BK=64, v_mfma_f32_32x32x16_f16.
// A: reg-staged from fp32 x (8 float4 -> cvt -> 4 ds_write_b128 per thread per tile) into
//    single-buffered As (16 KB). Same LDS slot/swizzle map as R0's DMA staging.
// B: global_load_lds DMA from f16 wh, double-buffered Bs (2 x 16 KB) — B(t+1) issued during
//    tile t, guarded by vmcnt(4) (in-order retirement: compiler's vmcnt(0) before the A-cvt
//    drains A loads (newest) and B(t) (older); only B(t+1)'s 4 ops remain in flight).
// Raw s_barrier (no __syncthreads vmcnt(0) drain); 3 blocks/CU via 48 KB LDS +
// __launch_bounds__(256,3) -> cross-block overlap hides the A-load latency (m114).
// LDS chunk map (per operand, 16 chunks of 1 KB): chunk = 8 rows x 8 16B-kchunks,
// slot(rr,kc) = rr*8 + (kc^rr); stage lane i -> row i>>3, kchunk (i&7)^(i>>3).
__global__ __launch_bounds__(256, 3) void gemm_f16(const float* __restrict__ X, const f16* __restrict__ B,
                                                   const int* __restrict__ pb,
                                                   const float* __restrict__ psw, const float* __restrict__ psb,
                                                   float* __restrict__ out) {
    __shared__ f16 As[128 * 64];        // 16 KB, single-buffered (reg-staged)
    __shared__ f16 Bs[2][128 * 64];     // 2 x 16 KB, double-buffered (DMA)

    const int tid  = threadIdx.x;
    const int wave = tid >> 6;
    const int lane = tid & 63;
    const int wm   = wave >> 1;          // 2x2 waves of 64x64
    const int wn   = wave & 1;
    const int half = lane >> 5;          // 0/1
    const int l32  = lane & 31;

    // XCD-bijective swizzle: 2048 wgs, 8 XCDs, 256 per XCD. Within an XCD the 32
    // concurrent blocks share one A panel (by fixed, bx sweeps) -> A L2-resident.
    const int bid = blockIdx.x;
    const int swz = (bid & 7) * 256 + (bid >> 3);
    const int bx  = swz & 31;            // N tiles: 32
    const int by  = swz >> 5;            // M tiles: 64
    const int mbase = by * 128;
    const int nbase = bx * 128;

    // staging: lane i fills slot i of a chunk -> row i>>3 (in-chunk), kchunk (i&7)^(i>>3)
    const int srow = lane >> 3;                    // 0..7
    const int skc  = (lane & 7) ^ srow;            // 16B k-chunk index 0..7

    // wave w stages rows [w*32, w*32+32) for both operands (chunks 4w..4w+3)
    const float* aP[4]; const f16* bP[4]; f16* aD[4];
#pragma unroll
    for (int j = 0; j < 4; j++) {
        aP[j] = X + (size_t)(mbase + wave * 32 + j * 8 + srow) * K_DIM + skc * 8;
        bP[j] = B + (size_t)(nbase + wave * 32 + j * 8 + srow) * K_DIM + skc * 8;
        aD[j] = As + (wave * 4 + j) * 512 + lane * 8;
    }

    f32x16 acc[2][2] = {};

    // fragment read bases: for subtile tt, row r = w{m,n}*64 + tt*32 + l32
    // addr(halves) = (r>>3)*512 + (r&7)*64 + ((kc ^ (r&7)))*8, kc = kk*2 + half
    int abase[2], bbase[2], arr[2], brr[2];
#pragma unroll
    for (int tt = 0; tt < 2; tt++) {
        int ra = wm * 64 + tt * 32 + l32;
        int rb = wn * 64 + tt * 32 + l32;
        abase[tt] = (ra >> 3) * 512 + (ra & 7) * 64;
        arr[tt]   = ra & 7;
        bbase[tt] = (rb >> 3) * 512 + (rb & 7) * 64;
        brr[tt]   = rb & 7;
    }

    // ---- prologue: B(0) DMA into buf 0 ----
#pragma unroll
    for (int j = 0; j < 4; j++)
        lds_async16(&Bs[0][(wave * 4 + j) * 512], bP[j]);

#pragma unroll 1
    for (int t = 0; t < 64; ++t) {
        const int koff = t * 64;

        // 1) A loads (fp32): 8 x float4
        float4 va[4][2];
#pragma unroll
        for (int j = 0; j < 4; j++) {
            const float4* p = (const float4*)(aP[j] + koff);
            va[j][0] = p[0]; va[j][1] = p[1];
        }
        // 2) cvt + ds_write (compiler inserts its own vmcnt drain before first use)
#pragma unroll
        for (int j = 0; j < 4; j++) {
            f16x8 h;
            h[0] = (f16)va[j][0].x; h[1] = (f16)va[j][0].y; h[2] = (f16)va[j][0].z; h[3] = (f16)va[j][0].w;
            h[4] = (f16)va[j][1].x; h[5] = (f16)va[j][1].y; h[6] = (f16)va[j][1].z; h[7] = (f16)va[j][1].w;
            *(f16x8*)aD[j] = h;
        }
        // 3) B(t+1) DMA into the other buffer (released by the end-of-(t-1) barrier)
        {
            const int kn = (t < 63 ? t + 1 : 63) * 64;   // last iter: harmless reload
            f16* bN = &Bs[(t + 1) & 1][0];
#pragma unroll
            for (int j = 0; j < 4; j++)
                lds_async16(bN + (wave * 4 + j) * 512, bP[j] + kn);
        }
        // 4) guard: B(t) landed (older than the 4 in-flight B(t+1) ops); A writes visible
        asm volatile("s_waitcnt vmcnt(4)" ::: "memory");
        asm volatile("s_waitcnt lgkmcnt(0)" ::: "memory");
        __builtin_amdgcn_sched_barrier(0);
        __builtin_amdgcn_s_barrier();
        __builtin_amdgcn_sched_barrier(0);

        // 5) compute: 4 x (K=16) MFMA steps on As, Bs[t&1]
        const f16* bC = &Bs[t & 1][0];
#pragma unroll
        for (int kk = 0; kk < 4; ++kk) {
            const int kc = kk * 2 + half;
            f16x8 af[2], bf[2];
#pragma unroll
            for (int tt = 0; tt < 2; tt++) {
                af[tt] = *(const f16x8*)&As[abase[tt] + ((kc ^ arr[tt])) * 8];
                bf[tt] = *(const f16x8*)&bC[bbase[tt] + ((kc ^ brr[tt])) * 8];
            }
#pragma unroll
            for (int mt = 0; mt < 2; mt++)
#pragma unroll
                for (int nt = 0; nt < 2; nt++)
                    acc[mt][nt] = __builtin_amdgcn_mfma_f32_32x32x16_f16(af[mt], bf[nt], acc[mt][nt], 0, 0, 0);
        }

        // 6) all waves done reading before next tile's As writes / B reuse
        __builtin_amdgcn_s_barrier();
        __builtin_amdgcn_sched_barrier(0);
    }

    asm volatile("s_waitcnt vmcnt(0)" ::: "memory");   // drain trailing dummy B prefetch

    const float sw = *psw;
    const float sb = *psb;

    // C/D layout (m74/m101): col = lane&31, row = (reg&3) + 8*(reg>>2) + 4*(lane>>5)
#pragma unroll
    for (int nt = 0; nt < 2; nt++) {
        const int gcol = nbase + wn * 64 + nt * 32 + l32;
        const int p    = pb[gcol >> 1];
        const int nib  = (gcol & 1) ? (p & 15) : ((p >> 4) & 15);
        const float bias = sb * (float)(nib - 8);
#pragma unroll
        for (int mt = 0; mt < 2; mt++) {
            const int rbase = mbase + wm * 64 + mt * 32 + half * 4;
#pragma unroll
            for (int g = 0; g < 4; g++) {
                float* o = out + (size_t)(rbase + g * 8) * N_DIM + gcol;
#pragma unroll
                for (int r = 0; r < 4; r++)
                    o[(size_t)r * N_DIM] = sw * acc[mt][nt][g * 4 + r] + bias;
            }
        }
    }
}

// ---- correct-but-slow fallback if workspace is too small for the f16 weight copy ----
__global__ __launch_bounds__(256) void gemm_fallback(const float* __restrict__ x, const int* __restrict__ pw,
                                                     const int* __restrict__ pb,
                                                     const float* __restrict__ psw, const float* __restrict__ psb,
                                                     float* __restrict__ out) {
    __shared__ float As[16][17];
    __shared__ float Bs[16][17];
    const int tx = threadIdx.x & 15, ty = threadIdx.x >> 4;
    const int row = blockIdx.y * 16 + ty;   // m
    const int col = blockIdx.x * 16 + tx;   // n
    float acc = 0.f;
    for (int k0 = 0; k0 < K_DIM; k0 += 16) {
        As[ty][tx] = x[(size_t)row * K_DIM + k0 + tx];
        const int nrow = blockIdx.x * 16 + ty;
        const int k = k0 + tx;
        const int p = pw[((size_t)nrow * K_DIM + k) >> 1];
        const int nib = (k & 1) ? (p & 15) : ((p >> 4) & 15);
        Bs[ty][tx] = (float)(nib - 8);
        __syncthreads();
#pragma unroll
        for (int kk = 0; kk < 16; kk++)
            acc += As[ty][kk] * Bs[tx][kk];
        __syncthreads();
    }
    const float sw = *psw, sb = *psb;
    const int p = pb[col >> 1];
    const int nib = (col & 1) ? (p & 15) : ((p >> 4) & 15);
    out[(size_t)row * N_DIM + col] = sw * acc + sb * (float)(nib - 8);
}

extern "C" void kernel_launch(void* const* d_in, const int* in_sizes, int n_in,
                              void* d_out, int out_size, void* d_ws, size_t ws_size,
                              hipStream_t stream) {
    (void)in_sizes; (void)n_in; (void)out_size;
    const float* x   = (const float*)d_in[0];
    const int*   pw  = (const int*)d_in[1];
    const int*   pb  = (const int*)d_in[2];
    const float* psw = (const float*)d_in[3];
    const float* psb = (const float*)d_in[4];
    float* out = (float*)d_out;

    const size_t wh_bytes = (size_t)N_DIM * K_DIM * sizeof(f16);   // 33.6 MB

    if (ws_size >= wh_bytes) {
        f16* wh = (f16*)d_ws;
        cvt_w_kernel<<<((size_t)N_DIM * K_DIM / 2) / 4 / 256, 256, 0, stream>>>(pw, wh);
        gemm_f16<<<dim3((N_DIM / 128) * (M_DIM / 128)), 256, 0, stream>>>(x, wh, pb, psw, psb, out);
    } else {
        gemm_fallback<<<dim3(N_DIM / 16, M_DIM / 16), 256, 0, stream>>>(x, pw, pb, psw, psb, out);
    }
}